// Round 10
// baseline (124.108 us; speedup 1.0000x reference)
//
#include <hip/hip_runtime.h>

#define PNUM 128
#define BATCH 8192
#define WPB 4                      // waves per block, 1 batch per wave
#define GRID1 (BATCH / WPB)        // 2048 blocks of 256 threads

typedef _Float16 h2 __attribute__((ext_vector_type(2)));
typedef _Float16 h4 __attribute__((ext_vector_type(4)));

// f32x2 -> f16x2 (RTZ), bit-cast around clang's __fp16/_Float16 vec mismatch
__device__ __forceinline__ h2 cvt2(float x, float y) {
    return __builtin_bit_cast(h2, __builtin_amdgcn_cvt_pkrtz(x, y));
}

// Packed smooth-L1 term, both coords, f32-accumulated. 5 packed VALU ops:
// v_pk_add (d=p-q), v_and_b32 (a=|d|), v_pk_min (m=min(a,1)),
// v_pk_fma (t=a-0.5m), v_dot2_f32_f16 (acc += m.t).
// p may live in an SGPR (readlane broadcast) - VOP3P allows 1 scalar src.
__device__ __forceinline__ void unit(h2 p, h2 q, float& acc) {
    h2 d = p - q;
    h2 a = __builtin_bit_cast(h2, __builtin_bit_cast(unsigned, d) & 0x7fff7fffu);
    h2 m = __builtin_elementwise_min(a, (h2)(_Float16)1.0f);
    h2 t = __builtin_elementwise_fma(m, (h2)(_Float16)-0.5f, a);
    acc = __builtin_amdgcn_fdot2(m, t, acc, false);
}

__device__ __forceinline__ h2 lo2(h4 v) { return __builtin_shufflevector(v, v, 0, 1); }
__device__ __forceinline__ h2 hi2(h4 v) { return __builtin_shufflevector(v, v, 2, 3); }

// readlane broadcast of a packed f16 pair (compile-time lane after unroll)
__device__ __forceinline__ h2 bcast(unsigned v, int lane) {
    return __builtin_bit_cast(h2, __builtin_amdgcn_readlane((int)v, lane));
}

// One WAVE per batch, both preds. Lane k owns shifts {2k,2k+1}.
// gt ring (doubled, f16) in per-wave LDS -> 2x ds_read_b64 sliding gather/hh.
// pred rows live in per-lane VGPRs (lane j holds points {2j,2j+1});
// per-hh broadcast via v_readlane -> SGPR operand (zero DS traffic for preds).
__global__ __launch_bounds__(64 * WPB, 6) void match_fused(
        const float* __restrict__ pred0,
        const float* __restrict__ pred1,
        const float* __restrict__ gt,
        float* __restrict__ out) {
    __shared__ __align__(16) h4 ring[WPB][128];   // doubled gt ring, 1 KB/wave

    const int t = threadIdx.x;
    const int k = t & 63;
    const int w = __builtin_amdgcn_readfirstlane(t >> 6);
    const int b = blockIdx.x * WPB + w;

    h4* ring4 = ring[w];

    // ---- stage gt -> LDS (own wave's region; no barrier), preds -> registers ----
    const float4* gv4 = (const float4*)(gt    + (size_t)b * (PNUM * 2));
    const float4* p0v = (const float4*)(pred0 + (size_t)b * (PNUM * 2));
    const float4* p1v = (const float4*)(pred1 + (size_t)b * (PNUM * 2));
    {
        float4 g = gv4[k];
        h2 c0 = cvt2(g.x, g.y), c1 = cvt2(g.z, g.w);
        h4 gh = {c0.x, c0.y, c1.x, c1.y};
        ring4[k] = gh; ring4[k + 64] = gh;
    }
    uint2 P0u, P1u;   // this lane's pred points {2k, 2k+1}, packed f16
    {
        float4 p = p0v[k];
        P0u.x = __builtin_bit_cast(unsigned, cvt2(p.x, p.y));
        P0u.y = __builtin_bit_cast(unsigned, cvt2(p.z, p.w));
        p = p1v[k];
        P1u.x = __builtin_bit_cast(unsigned, cvt2(p.x, p.y));
        P1u.y = __builtin_bit_cast(unsigned, cvt2(p.z, p.w));
    }

    h4 W = ring4[k];                     // ring points {2k, 2k+1}
    float a00 = 0.f, a01 = 0.f, a10 = 0.f, a11 = 0.f;

#pragma unroll 4
    for (int hh = 0; hh < 32; ++hh) {    // j = 4*hh .. 4*hh+3
        h4 na = ring4[k + 2 * hh + 1];   // adjacent h4 pair -> ds_read2_b64-able
        h4 nb = ring4[k + 2 * hh + 2];

        // pred points 4hh..4hh+3 via readlane (lanes 2hh, 2hh+1 hold them)
        h2 p0a = bcast(P0u.x, 2 * hh),     p0b = bcast(P0u.y, 2 * hh);
        h2 p0c = bcast(P0u.x, 2 * hh + 1), p0d = bcast(P0u.y, 2 * hh + 1);
        h2 p1a = bcast(P1u.x, 2 * hh),     p1b = bcast(P1u.y, 2 * hh);
        h2 p1c = bcast(P1u.x, 2 * hh + 1), p1d = bcast(P1u.y, 2 * hh + 1);

        h2 Wl = lo2(W), Wh = hi2(W), Al = lo2(na), Ah = hi2(na), Bl = lo2(nb);

        // pred0: shift 2k, then 2k+1
        unit(p0a, Wl, a00); unit(p0b, Wh, a00); unit(p0c, Al, a00); unit(p0d, Ah, a00);
        unit(p0a, Wh, a01); unit(p0b, Al, a01); unit(p0c, Ah, a01); unit(p0d, Bl, a01);
        // pred1
        unit(p1a, Wl, a10); unit(p1b, Wh, a10); unit(p1c, Al, a10); unit(p1d, Ah, a10);
        unit(p1a, Wh, a11); unit(p1b, Al, a11); unit(p1c, Ah, a11); unit(p1d, Bl, a11);

        W = nb;
    }

    // per-pred min over lane's 2 shifts, then over the wave
    float r0 = fminf(a00, a01);
    float r1 = fminf(a10, a11);
#pragma unroll
    for (int m = 32; m > 0; m >>= 1) {
        r0 = fminf(r0, __shfl_xor(r0, m, 64));
        r1 = fminf(r1, __shfl_xor(r1, m, 64));
    }

    __shared__ float bsum[WPB];
    if (k == 0) bsum[w] = r0 + r1;
    __syncthreads();
    if (t == 0) {
        float blockpart = bsum[0] + bsum[1] + bsum[2] + bsum[3];
        // relaxed device-scope atomic; NO fence (R5 lesson: fences -> L2 writeback storm)
        atomicAdd(out, blockpart * (1.0f / (2.0f * BATCH * PNUM)));
    }
}

extern "C" void kernel_launch(void* const* d_in, const int* in_sizes, int n_in,
                              void* d_out, int out_size, void* d_ws, size_t ws_size,
                              hipStream_t stream) {
    const float* pred0 = (const float*)d_in[0];
    const float* pred1 = (const float*)d_in[1];
    const float* gt    = (const float*)d_in[2];
    float* out = (float*)d_out;

    (void)hipMemsetAsync(out, 0, sizeof(float), stream);   // out is 0xAA-poisoned
    match_fused<<<GRID1, 64 * WPB, 0, stream>>>(pred0, pred1, gt, out);
}

// Round 11
// 116.613 us; speedup vs baseline: 1.0643x; 1.0643x over previous
//
#include <hip/hip_runtime.h>

#define PNUM 128
#define BATCH 8192
#define WPB 4                        // waves per block; 2 batches per wave
#define GRID1 (BATCH / (2 * WPB))    // 1024 blocks of 256 threads

typedef _Float16 h2 __attribute__((ext_vector_type(2)));
typedef _Float16 h4 __attribute__((ext_vector_type(4)));
typedef _Float16 h8 __attribute__((ext_vector_type(8)));

__device__ __forceinline__ h2 cvt2(float x, float y) {
    return __builtin_bit_cast(h2, __builtin_amdgcn_cvt_pkrtz(x, y));
}
__device__ __forceinline__ h4 cvt4(float4 v) {
    h2 a = cvt2(v.x, v.y), b = cvt2(v.z, v.w);
    return (h4){a.x, a.y, b.x, b.y};
}

// Packed smooth-L1 term, both coords, f32-accumulated. 5 packed VALU ops:
// v_pk_add, v_and_b32 (|d|), v_pk_min, v_pk_fma, v_dot2_f32_f16.
__device__ __forceinline__ void unit(h2 p, h2 q, float& acc) {
    h2 d = p - q;
    h2 a = __builtin_bit_cast(h2, __builtin_bit_cast(unsigned, d) & 0x7fff7fffu);
    h2 m = __builtin_elementwise_min(a, (h2)(_Float16)1.0f);
    h2 t = __builtin_elementwise_fma(m, (h2)(_Float16)-0.5f, a);
    acc = __builtin_amdgcn_fdot2(m, t, acc, false);
}

__device__ __forceinline__ h2 lo2(h4 v) { return __builtin_shufflevector(v, v, 0, 1); }
__device__ __forceinline__ h2 hi2(h4 v) { return __builtin_shufflevector(v, v, 2, 3); }
__device__ __forceinline__ h4 lo4(h8 v) { return __builtin_shufflevector(v, v, 0, 1, 2, 3); }
__device__ __forceinline__ h4 hi4(h8 v) { return __builtin_shufflevector(v, v, 4, 5, 6, 7); }
__device__ __forceinline__ h2 el2(h8 v, int i) {
    return (h2){v[2 * i], v[2 * i + 1]};
}

// One WAVE per 2 batches (one per 32-lane half). Lane (h,kk) owns shifts
// {4kk..4kk+3} of batch h. Per hh (4 j): 1 lane-dense gather b128 (4 new ring
// points) + 2 half-uniform pred b128 = 3 DS instr serving 32 smooth-L1 units
// (160 VALU). All data flow within each half-wave -> in-order DS, no barrier.
__global__ __launch_bounds__(64 * WPB, 4) void match_fused(
        const float* __restrict__ pred0,
        const float* __restrict__ pred1,
        const float* __restrict__ gt,
        float* __restrict__ out) {
    __shared__ __align__(16) h4 ring [WPB][2][128];     // doubled gt ring, 1KB/batch
    __shared__ __align__(16) h4 preds[WPB][2][2][64];   // [pred][entry], .5KB each

    const int t  = threadIdx.x;
    const int k  = t & 63;
    const int w  = __builtin_amdgcn_readfirstlane(t >> 6);
    const int h  = k >> 5;                  // which batch of this wave's pair
    const int kk = k & 31;
    const int b  = 2 * (blockIdx.x * WPB + w) + h;

    h4* ring4 = ring[w][h];
    h4* q0 = preds[w][h][0];
    h4* q1 = preds[w][h][1];

    // ---- stage this half's batch (gt doubled; preds) ----
    const float4* gv4 = (const float4*)(gt    + (size_t)b * (PNUM * 2));
    const float4* p0v = (const float4*)(pred0 + (size_t)b * (PNUM * 2));
    const float4* p1v = (const float4*)(pred1 + (size_t)b * (PNUM * 2));
    {
        h4 v = cvt4(gv4[kk]);      ring4[kk]      = v; ring4[kk + 64] = v;
        v    = cvt4(gv4[kk + 32]); ring4[kk + 32] = v; ring4[kk + 96] = v;
        q0[kk]      = cvt4(p0v[kk]);
        q0[kk + 32] = cvt4(p0v[kk + 32]);
        q1[kk]      = cvt4(p1v[kk]);
        q1[kk + 32] = cvt4(p1v[kk + 32]);
    }

    const h8* q0_8 = (const h8*)q0;         // 32 entries of 4 points
    const h8* q1_8 = (const h8*)q1;

    // window: gt points {4kk+4hh .. 4kk+4hh+7} as w0,w1 (cur) + w2,w3 (incoming)
    h8 wi = *(const h8*)&ring4[2 * kk];     // 16B-aligned
    h4 w0 = lo4(wi), w1 = hi4(wi);

    float r00 = 0.f, r01 = 0.f, r02 = 0.f, r03 = 0.f;   // pred0, shifts 4kk+0..3
    float r10 = 0.f, r11 = 0.f, r12 = 0.f, r13 = 0.f;   // pred1

#pragma unroll 4
    for (int hh = 0; hh < 32; ++hh) {
        h8 n  = *(const h8*)&ring4[2 * kk + 2 * hh + 2];  // 4 new points, b128
        h8 P0 = q0_8[hh];                                  // pred points 4hh..4hh+3
        h8 P1 = q1_8[hh];
        h4 w2 = lo4(n), w3 = hi4(n);

        h2 A0 = lo2(w0), A1 = hi2(w0), A2 = lo2(w1), A3 = hi2(w1);
        h2 A4 = lo2(w2), A5 = hi2(w2), A6 = lo2(w3);
        h2 p0a = el2(P0, 0), p0b = el2(P0, 1), p0c = el2(P0, 2), p0d = el2(P0, 3);
        h2 p1a = el2(P1, 0), p1b = el2(P1, 1), p1c = el2(P1, 2), p1d = el2(P1, 3);

        // shift 4kk+r uses gt points A[r .. r+3] against pred j=4hh..4hh+3
        unit(p0a, A0, r00); unit(p0b, A1, r00); unit(p0c, A2, r00); unit(p0d, A3, r00);
        unit(p0a, A1, r01); unit(p0b, A2, r01); unit(p0c, A3, r01); unit(p0d, A4, r01);
        unit(p0a, A2, r02); unit(p0b, A3, r02); unit(p0c, A4, r02); unit(p0d, A5, r02);
        unit(p0a, A3, r03); unit(p0b, A4, r03); unit(p0c, A5, r03); unit(p0d, A6, r03);

        unit(p1a, A0, r10); unit(p1b, A1, r10); unit(p1c, A2, r10); unit(p1d, A3, r10);
        unit(p1a, A1, r11); unit(p1b, A2, r11); unit(p1c, A3, r11); unit(p1d, A4, r11);
        unit(p1a, A2, r12); unit(p1b, A3, r12); unit(p1c, A4, r12); unit(p1d, A5, r12);
        unit(p1a, A3, r13); unit(p1b, A4, r13); unit(p1c, A5, r13); unit(p1d, A6, r13);

        w0 = w2; w1 = w3;
    }

    // min over this lane's 4 shifts (per pred), then across the 32-lane half
    float m0 = fminf(fminf(r00, r01), fminf(r02, r03));
    float m1 = fminf(fminf(r10, r11), fminf(r12, r13));
#pragma unroll
    for (int m = 16; m > 0; m >>= 1) {
        m0 = fminf(m0, __shfl_xor(m0, m, 64));
        m1 = fminf(m1, __shfl_xor(m1, m, 64));
    }
    float s = m0 + m1;              // this batch's min0+min1 (lanes 0 and 32 hold it)
    s += __shfl_xor(s, 32, 64);     // combine the wave's two batches

    __shared__ float bsum[WPB];
    if (k == 0) bsum[w] = s;
    __syncthreads();
    if (t == 0) {
        float blockpart = bsum[0] + bsum[1] + bsum[2] + bsum[3];
        // relaxed device-scope atomic; NO fence (R5 lesson: fences -> writeback storm)
        atomicAdd(out, blockpart * (1.0f / (2.0f * BATCH * PNUM)));
    }
}

extern "C" void kernel_launch(void* const* d_in, const int* in_sizes, int n_in,
                              void* d_out, int out_size, void* d_ws, size_t ws_size,
                              hipStream_t stream) {
    const float* pred0 = (const float*)d_in[0];
    const float* pred1 = (const float*)d_in[1];
    const float* gt    = (const float*)d_in[2];
    float* out = (float*)d_out;

    (void)hipMemsetAsync(out, 0, sizeof(float), stream);   // out is 0xAA-poisoned
    match_fused<<<GRID1, 64 * WPB, 0, stream>>>(pred0, pred1, gt, out);
}